// Round 6
// baseline (817.373 us; speedup 1.0000x reference)
//
#include <hip/hip_runtime.h>
#include <hip/hip_bf16.h>

typedef __hip_bfloat16 bf16;
typedef __attribute__((ext_vector_type(8))) short bf16x8;
typedef __attribute__((ext_vector_type(4))) float f32x4;

#define N_NODES 50000
#define E_EDGES 800000
#define EA (E_EDGES + N_NODES)   // 850000 edges incl self-loops
#define HC 128                   // heads*dim
#define HEADS 4
#define DIM 32
#define DIM2 16
#define NCLS 6
#define SLOPE 0.2f
#define XN (N_NODES * HC)
#define GM 32                    // nodes per GEMM block
#define HSTRIDE 152              // padded ushort stride (304B)
#define WSWZ_L 32768             // swizzled weight ushorts per layer (256*128)
#define NCHUNK ((N_NODES + 1023) / 1024)   // 49

#define P_CVTI (2 * E_EDGES)     // 1,600,000
#define P_PRM  6390              // params after Wl/Wr (j in [98304,104694))
#define P_WSWZ (3 * WSWZ_L)      // 98,304
#define P_TOT  (P_CVTI + P_PRM + P_WSWZ)

__device__ __forceinline__ float b2f(bf16 v) { return __bfloat162float(v); }
__device__ __forceinline__ unsigned short f2bfu(float f) {
    bf16 b = __float2bfloat16(f);
    return *(unsigned short*)&b;
}
__device__ __forceinline__ unsigned packbf(float a, float b) {
    return (unsigned)f2bfu(a) | ((unsigned)f2bfu(b) << 16);
}

// ---- per-block inline dtype detector (reads ~6KB, L2-hot, deterministic) ----
// isf32: float tensors are fp32 (else bf16). is64: edge_index is int64.
__device__ __forceinline__ void block_detect(const void* wptr, const void* eptr,
                                             int* det, int& isf32, int& is64) {
    int tid = threadIdx.x;            // blockDim.x == 256
    if (tid == 0) { det[0] = 0; det[1] = 0; }
    __syncthreads();
    const unsigned short* w = (const unsigned short*)wptr;
    int badf = 0;
    for (int i = tid; i < 1024; i += 256) {
        unsigned v = w[i];
        unsigned ex = (v >> 7) & 0xFF;
        if (v != 0 && (ex < 90 || ex > 150)) badf++;
    }
    const int* ei = (const int*)eptr;
    int nz = 0;
    for (int i = tid; i < 1024; i += 256) {
        if (ei[2 * i + 1] != 0) nz++;
    }
    if (badf) atomicAdd(&det[0], badf);
    if (nz)   atomicAdd(&det[1], nz);
    __syncthreads();
    isf32 = det[0] > 100;   // fp32: ~390 expected; bf16: ~0
    is64  = det[1] < 100;   // int64: high words all 0; int32: ~512 nonzero
}

// ---- fused front-end: edge cvt + degree histogram, param cvt, weight swizzle --
__global__ __launch_bounds__(256) void k_prep(
        const void* eraw, const void* sWl, const void* sWr,
        const void* sbl, const void* sbr, const void* satt, const void* scb,
        const void* sW1, const void* sb1, const void* sW2, const void* sb2,
        const void* sW3, const void* sb3,
        int* __restrict__ eidx, int* __restrict__ off,
        float* __restrict__ prm, unsigned short* __restrict__ wswz) {
    __shared__ int det[2];
    int isf32, is64;
    block_detect(sWl, eraw, det, isf32, is64);

    int i = blockIdx.x * 256 + threadIdx.x;
    if (i < P_CVTI) {
        int v = is64 ? (int)((const long long*)eraw)[i] : ((const int*)eraw)[i];
        if (v < 0) v = 0;
        if (v >= N_NODES) v = N_NODES - 1;
        eidx[i] = v;
        if (i >= E_EDGES) atomicAdd(&off[v], 1);   // dst histogram (real edges)
        return;
    }
    i -= P_CVTI;
    if (i < P_PRM) {
        int j = i + 98304;
        const void* src; float* dst; int o;
        if      (j < 98688)  { src = sbl;  dst = prm + 98304;  o = j - 98304; }
        else if (j < 99072)  { src = sbr;  dst = prm + 98688;  o = j - 98688; }
        else if (j < 99456)  { src = satt; dst = prm + 99072;  o = j - 99072; }
        else if (j < 99840)  { src = scb;  dst = prm + 99456;  o = j - 99456; }
        else if (j < 103936) { src = sW1;  dst = prm + 99840;  o = j - 99840; }
        else if (j < 103968) { src = sb1;  dst = prm + 103936; o = j - 103936; }
        else if (j < 104480) { src = sW2;  dst = prm + 103968; o = j - 103968; }
        else if (j < 104496) { src = sb2;  dst = prm + 104480; o = j - 104480; }
        else if (j < 104688) { src = sW3;  dst = prm + 104496; o = j - 104496; }
        else                 { src = sb3;  dst = prm + 104688; o = j - 104688; }
        dst[o] = isf32 ? ((const float*)src)[o] : b2f(((const bf16*)src)[o]);
        return;
    }
    i -= P_PRM;
    if (i >= P_WSWZ) return;
    // weight swizzle straight from raw Wl/Wr (dtype branch)
    int L = i / WSWZ_L;
    int e = i % WSWZ_L;
    int ntile = e >> 11;
    int r2 = e & 2047;
    int ks = r2 >> 9;
    int r3 = r2 & 511;
    int lane = r3 >> 3;
    int j = r3 & 7;
    int col = ntile * 16 + (lane & 15);       // 0..255 combined (Wl | Wr)
    int k = ks * 32 + (lane >> 4) * 8 + j;
    const void* src = (col < HC) ? sWl : sWr;
    int idx = L * HC * HC + k * HC + (col & (HC - 1));
    float v = isf32 ? ((const float*)src)[idx] : b2f(((const bf16*)src)[idx]);
    wswz[i] = f2bfu(v);
}

// ---- parallel scan: stage 1 (block-local, incl +1 self-loop per node) ----
__global__ __launch_bounds__(1024) void k_scan1(int* __restrict__ off, int* __restrict__ part) {
    __shared__ int s[1024];
    int tid = threadIdx.x;
    int i = blockIdx.x * 1024 + tid;
    int v = (i < N_NODES) ? off[i] + 1 : 0;     // +1: self-loop
    s[tid] = v;
    __syncthreads();
    for (int o = 1; o < 1024; o <<= 1) {
        int t = (tid >= o) ? s[tid - o] : 0;
        __syncthreads();
        s[tid] += t;
        __syncthreads();
    }
    if (i < N_NODES) off[i] = s[tid] - v;       // exclusive
    if (tid == 1023) part[blockIdx.x] = s[1023];
}

// ---- stage 2: per-block wave-reduce of preceding chunk totals, then add ----
__global__ __launch_bounds__(1024) void k_scan3(int* __restrict__ off, const int* __restrict__ part) {
    __shared__ int sbase;
    int tid = threadIdx.x;
    if (tid < 64) {
        int v = (tid < NCHUNK && tid < (int)blockIdx.x) ? part[tid] : 0;
        for (int o = 32; o > 0; o >>= 1) v += __shfl_down(v, o);
        if (tid == 0) sbase = v;
    }
    __syncthreads();
    int i = blockIdx.x * 1024 + tid;
    if (i < N_NODES) off[i] += sbase;
    if (i == 0) off[N_NODES] = EA;
}

__global__ void k_scatter(const int* __restrict__ eidx, const int* __restrict__ off,
                          int* __restrict__ fill, int* __restrict__ csrsrc) {
    int e = blockIdx.x * blockDim.x + threadIdx.x;
    if (e >= EA) return;
    int src, dst;
    if (e < E_EDGES) { src = eidx[e]; dst = eidx[E_EDGES + e]; }
    else             { src = dst = e - E_EDGES; }
    int pos = off[dst] + atomicAdd(&fill[dst], 1);
    if (pos >= 0 && pos < EA) csrsrc[pos] = src;
}

// ------- MFMA GEMM: xl(bf16, HEAD-MAJOR) cols 0..127, xr(fp32) cols 128..255 --
// xlbf layout: ((head*N + node)*16 + pair) uints -> per-head 3.2MB (L2-resident
// during k_attn's per-head gather). hsrc: detect_in ? raw x : packed-bf16 h.
__global__ __launch_bounds__(256) void k_gemm_mfma(
        const void* __restrict__ hsrc, const void* wdet, const void* edet,
        int detect_in,
        const unsigned short* __restrict__ wswz,
        const float* __restrict__ bl, const float* __restrict__ br,
        unsigned* __restrict__ xlbf, float* __restrict__ xr) {
    __shared__ unsigned short hs[GM * HSTRIDE];   // 9728 B
    __shared__ int det[2];
    int tid = threadIdx.x;
    int wave = tid >> 6, lane = tid & 63;
    long row0 = (long)blockIdx.x * GM;

    int f32in = 0;
    if (detect_in) {
        int is64d;
        block_detect(wdet, edet, det, f32in, is64d);
    }

    if (f32in) {
        for (int idx = tid; idx < GM * 64; idx += 256) {
            int r = idx >> 6, cp = idx & 63;
            float v0 = 0.f, v1 = 0.f;
            if (row0 + r < N_NODES) {
                const float2 hv = ((const float2*)((const float*)hsrc + (row0 + r) * HC))[cp];
                v0 = hv.x; v1 = hv.y;
            }
            *(unsigned*)&hs[r * HSTRIDE + cp * 2] = packbf(v0, v1);
        }
    } else {
        for (int idx = tid; idx < GM * 64; idx += 256) {
            int r = idx >> 6, cp = idx & 63;
            unsigned u = 0;
            if (row0 + r < N_NODES)
                u = ((const unsigned*)hsrc)[(row0 + r) * (HC / 2) + cp];
            *(unsigned*)&hs[r * HSTRIDE + cp * 2] = u;
        }
    }
    __syncthreads();

    int q = lane >> 4, l16 = lane & 15;
    for (int nt = 0; nt < 4; nt++) {
        int colbase = wave * 64 + nt * 16;
        int col = colbase + l16;          // 0..255 combined
        int ntile = colbase >> 4;
        f32x4 acc0 = {0.f, 0.f, 0.f, 0.f};
        f32x4 acc1 = {0.f, 0.f, 0.f, 0.f};
#pragma unroll
        for (int ks = 0; ks < 4; ks++) {
            bf16x8 bfrag = *(const bf16x8*)(wswz + (((ntile * 4 + ks) * 64 + lane) << 3));
            bf16x8 a0 = *(const bf16x8*)(hs + l16 * HSTRIDE + ks * 32 + q * 8);
            bf16x8 a1 = *(const bf16x8*)(hs + (16 + l16) * HSTRIDE + ks * 32 + q * 8);
            acc0 = __builtin_amdgcn_mfma_f32_16x16x32_bf16(a0, bfrag, acc0, 0, 0, 0);
            acc1 = __builtin_amdgcn_mfma_f32_16x16x32_bf16(a1, bfrag, acc1, 0, 0, 0);
        }
        if (col < HC) {
            float bias = bl[col];
            int head = col >> 5;
            int pair = (col >> 1) & 15;   // pair index within head (col even writes)
#pragma unroll
            for (int reg = 0; reg < 4; reg++) {
                float v0 = acc0[reg] + bias;
                float v1 = acc1[reg] + bias;
                float p0 = __shfl_xor(v0, 1);
                float p1 = __shfl_xor(v1, 1);
                if ((lane & 1) == 0) {
                    long n0 = row0 + q * 4 + reg;
                    long n1 = row0 + 16 + q * 4 + reg;
                    unsigned u0 = packbf(v0, p0);
                    unsigned u1 = packbf(v1, p1);
                    if (n0 < N_NODES) xlbf[((long)head * N_NODES + n0) * 16 + pair] = u0;
                    if (n1 < N_NODES) xlbf[((long)head * N_NODES + n1) * 16 + pair] = u1;
                }
            }
        } else {
            int c = col - HC;
            float bias = br[c];
#pragma unroll
            for (int reg = 0; reg < 4; reg++) {
                long n0 = row0 + q * 4 + reg;
                long n1 = row0 + 16 + q * 4 + reg;
                if (n0 < N_NODES) xr[n0 * HC + c] = acc0[reg] + bias;
                if (n1 < N_NODES) xr[n1 * HC + c] = acc1[reg] + bias;
            }
        }
    }
}

// --- GATv2 aggregation, PER-HEAD: wave = one (node,head); 16 lanes/edge-head. -
// Head is the slow grid dim -> co-resident blocks share a head -> gather
// working set = 3.2MB, fits every XCD L2. Depth-4 gather pipeline kept.
// out_bf16: write packed bf16 h (consumed by next gemm), else fp32 (for MLP)
__global__ __launch_bounds__(256) void k_attn(
        const unsigned* __restrict__ xlbf, const float* __restrict__ xr,
        const int* __restrict__ off, const int* __restrict__ csrsrc,
        const float* __restrict__ att, const float* __restrict__ cb,
        void* __restrict__ hout, int out_bf16) {
    int wave = threadIdx.x >> 6;
    int lane = threadIdx.x & 63;
    int unit = blockIdx.x * 4 + wave;        // 0 .. 4*N-1, heads contiguous
    int head = unit / N_NODES;
    int node = unit - head * N_NODES;
    int grp = lane >> 4;                     // edge phase 0..3
    int gl  = lane & 15;                     // channel-pair: ch = 2*gl, 2*gl+1

    float2 xv = *(const float2*)(xr + (long)node * HC + head * DIM + gl * 2);
    float2 av = *(const float2*)(att + head * DIM + gl * 2);

    int e0 = off[node], e1 = off[node + 1];
    if (e0 < 0) e0 = 0;
    if (e1 > EA) e1 = EA;
    if (e1 <= e0) {                          // defensive (self-loops guarantee >0)
        if (grp == 0) {
            if (out_bf16) ((unsigned*)hout)[(long)node * (HC / 2) + head * 16 + gl] = 0u;
            else *(float2*)((float*)hout + (long)node * HC + head * DIM + gl * 2)
                     = make_float2(0.f, 0.f);
        }
        return;
    }
    int klast = e1 - 1;
    const char* xlb = (const char*)(xlbf + (long)head * N_NODES * 16);
    unsigned glo = (unsigned)gl * 4u;
#define XLD(s) (*(const unsigned*)(xlb + (((unsigned)(s) << 6) + glo)))
#define CLMP(x) ((x) < klast ? (x) : klast)

    int k0 = e0 + grp;
    int sa = csrsrc[CLMP(k0)];
    int sb = csrsrc[CLMP(k0 + 4)];
    int sc = csrsrc[CLMP(k0 + 8)];
    int sd = csrsrc[CLMP(k0 + 12)];
    int sP = csrsrc[CLMP(k0 + 16)];
    unsigned u0 = XLD(sa);
    unsigned u1 = XLD(sb);
    unsigned u2 = XLD(sc);
    unsigned u3 = XLD(sd);

    float m = -1e30f, ssum = 0.f;
    float a0 = 0.f, a1 = 0.f;

    for (int kk = k0; kk < e1; kk += 4) {
        unsigned cur = u0;
        u0 = u1; u1 = u2; u2 = u3;
        u3 = XLD(sP);                     // edge kk+16 (index loaded last iter)
        sP = csrsrc[CLMP(kk + 20)];       // index for next iter's gather

        float x0 = __uint_as_float(cur << 16);
        float x1 = __uint_as_float(cur & 0xffff0000u);
        float m0 = x0 + xv.x, m1 = x1 + xv.y;
        float l0 = fmaxf(m0, SLOPE * m0), l1 = fmaxf(m1, SLOPE * m1);
        float p = l0 * av.x + l1 * av.y;
        p += __shfl_xor(p, 1);
        p += __shfl_xor(p, 2);
        p += __shfl_xor(p, 4);
        p += __shfl_xor(p, 8);
        float mn = fmaxf(m, p);
        float sc_ = __expf(m - mn);
        float ex = __expf(p - mn);
        ssum = ssum * sc_ + ex;
        a0 = a0 * sc_ + ex * x0;
        a1 = a1 * sc_ + ex * x1;
        m = mn;
    }
#undef XLD
#undef CLMP

#pragma unroll
    for (int d = 16; d <= 32; d <<= 1) {
        float mo = __shfl_xor(m, d);
        float so = __shfl_xor(ssum, d);
        float b0 = __shfl_xor(a0, d);
        float b1 = __shfl_xor(a1, d);
        float mn = fmaxf(m, mo);
        float s1f = __expf(m - mn);
        float s2f = __expf(mo - mn);
        ssum = ssum * s1f + so * s2f;
        a0 = a0 * s1f + b0 * s2f;
        a1 = a1 * s1f + b1 * s2f;
        m = mn;
    }

    if (grp == 0) {
        float inv = 1.f / (ssum + 1e-16f);
        float2 cv = *(const float2*)(cb + head * DIM + gl * 2);
        float o0 = fmaxf(a0 * inv + cv.x, 0.f);
        float o1 = fmaxf(a1 * inv + cv.y, 0.f);
        if (out_bf16) {
            ((unsigned*)hout)[(long)node * (HC / 2) + head * 16 + gl] = packbf(o0, o1);
        } else {
            *(float2*)((float*)hout + (long)node * HC + head * DIM + gl * 2)
                = make_float2(o0, o1);
        }
    }
}

// ---- fused MLP head: h3 = relu(relu(h @ W1 + b1) @ W2 + b2), 16 nodes/block --
__global__ __launch_bounds__(256) void k_mlp(
        const float* __restrict__ h, const float* __restrict__ W1,
        const float* __restrict__ b1, const float* __restrict__ W2,
        const float* __restrict__ b2, float* __restrict__ h3) {
    __shared__ float w1s[HC * DIM];       // 16 KB
    __shared__ float hs[16 * HC];         // 8 KB
    __shared__ float h2s[16 * DIM];       // 2 KB
    __shared__ float w2s[DIM * DIM2];     // 2 KB
    int tid = threadIdx.x;
    long row0 = (long)blockIdx.x * 16;
    for (int idx = tid; idx < HC * DIM; idx += 256) w1s[idx] = W1[idx];
    for (int idx = tid; idx < DIM * DIM2; idx += 256) w2s[idx] = W2[idx];
    for (int idx = tid; idx < 16 * HC; idx += 256) {
        long g = row0 * HC + idx;
        hs[idx] = (g < (long)N_NODES * HC) ? h[g] : 0.f;
    }
    __syncthreads();
#pragma unroll
    for (int p = 0; p < 2; p++) {
        int idx = tid + p * 256;
        int r = idx >> 5, c = idx & 31;
        float acc = b1[c];
        for (int k = 0; k < HC; k++) acc += hs[r * HC + k] * w1s[k * DIM + c];
        h2s[r * DIM + c] = acc > 0.f ? acc : 0.f;
    }
    __syncthreads();
    int r = tid >> 4, c = tid & 15;
    float acc = b2[c];
    for (int k = 0; k < DIM; k++) acc += h2s[r * DIM + k] * w2s[k * DIM2 + c];
    long row = row0 + r;
    if (row < N_NODES) h3[row * DIM2 + c] = acc > 0.f ? acc : 0.f;
}

// --- fused head, 2 threads/edge: pair (even=src, odd=dst) each gathers one ---
// --- h3 row (64B contiguous), stores its eout half; out0 via shfl_xor(1).  ---
__global__ __launch_bounds__(256) void k_out(
        const float* __restrict__ h3, const int* __restrict__ eidx,
        const float* __restrict__ W3, const float* __restrict__ b3,
        void* __restrict__ dout, const void* wdet, const void* edet) {
    __shared__ float w3s[2 * DIM2 * NCLS];
    __shared__ float bs[NCLS];
    __shared__ int det[2];
    int isf32, is64d;
    block_detect(wdet, edet, det, isf32, is64d);
    int tid = threadIdx.x;
    if (tid < 2 * DIM2 * NCLS) w3s[tid] = W3[tid];
    if (tid < NCLS) bs[tid] = b3[tid];
    __syncthreads();
    int idx = blockIdx.x * 256 + tid;     // grid covers exactly 2*E threads
    int e = idx >> 1, half = idx & 1;
    int node = eidx[half * E_EDGES + e];
    float4 t0, t1, t2, t3;
    {
        const float4* ps = (const float4*)(h3 + (long)node * DIM2);
        t0 = ps[0]; t1 = ps[1]; t2 = ps[2]; t3 = ps[3];
    }
    float v[DIM2];
    v[0] = t0.x;  v[1] = t0.y;  v[2] = t0.z;  v[3] = t0.w;
    v[4] = t1.x;  v[5] = t1.y;  v[6] = t1.z;  v[7] = t1.w;
    v[8] = t2.x;  v[9] = t2.y;  v[10] = t2.z; v[11] = t2.w;
    v[12] = t3.x; v[13] = t3.y; v[14] = t3.z; v[15] = t3.w;
    const float* wrow = w3s + half * DIM2 * NCLS;
    float o[NCLS];
#pragma unroll
    for (int j = 0; j < NCLS; j++) {
        float acc = half ? 0.f : bs[j];
#pragma unroll
        for (int k = 0; k < DIM2; k++) acc += v[k] * wrow[k * NCLS + j];
        o[j] = acc;
    }
#pragma unroll
    for (int j = 0; j < NCLS; j++) o[j] += __shfl_xor(o[j], 1);
    if (isf32) {
        float4* eo = (float4*)((float*)dout + (long)E_EDGES * NCLS
                               + (long)e * 32 + half * 16);
        eo[0] = t0; eo[1] = t1; eo[2] = t2; eo[3] = t3;
        if (!half) {
            float2* out0 = (float2*)dout;
            out0[(long)e * 3 + 0] = make_float2(o[0], o[1]);
            out0[(long)e * 3 + 1] = make_float2(o[2], o[3]);
            out0[(long)e * 3 + 2] = make_float2(o[4], o[5]);
        }
    } else {
        uint4 wa, wb;
        wa.x = packbf(v[0], v[1]);   wa.y = packbf(v[2], v[3]);
        wa.z = packbf(v[4], v[5]);   wa.w = packbf(v[6], v[7]);
        wb.x = packbf(v[8], v[9]);   wb.y = packbf(v[10], v[11]);
        wb.z = packbf(v[12], v[13]); wb.w = packbf(v[14], v[15]);
        uint4* eo = (uint4*)((bf16*)dout + (long)E_EDGES * NCLS)
                    + (long)e * 4 + half * 2;
        eo[0] = wa; eo[1] = wb;
        if (!half) {
            unsigned* out0 = (unsigned*)dout;
            out0[(long)e * 3 + 0] = packbf(o[0], o[1]);
            out0[(long)e * 3 + 1] = packbf(o[2], o[3]);
            out0[(long)e * 3 + 2] = packbf(o[4], o[5]);
        }
    }
}

extern "C" void kernel_launch(void* const* d_in, const int* in_sizes, int n_in,
                              void* d_out, int out_size, void* d_ws, size_t ws_size,
                              hipStream_t stream) {
    // ---- workspace layout (4-byte word offsets) ----
    float* wsf   = (float*)d_ws;
    float* h     = wsf + 16;                       // bf16-packed h layers 0-1; fp32 last
    float* xl    = h  + (long)N_NODES * HC;        // xlbf overlay; h3 overlay post-conv
    float* xr    = xl + (long)N_NODES * HC;
    float* prm   = xr + (long)N_NODES * HC;        // 110,000 (Wl/Wr slots unused)
    unsigned short* wswz = (unsigned short*)(prm + 110000);  // 3*32768 ushorts
    int*   eidx  = (int*)(wswz + P_WSWZ);          // 1,600,000
    int*   off   = eidx + 2 * E_EDGES;             // 50,001
    int*   fill  = off + (N_NODES + 1);            // 50,000
    int*   csr   = fill + N_NODES;                 // 850,000
    int*   part  = csr + EA;                       // 64
    unsigned* xlbf = (unsigned*)xl;                // head-major: [4][N][16] uints
    float* h3 = xl;                                // overlay (free after last attn)

    float* pbl = prm + 98304;
    float* pbr = prm + 98688;
    float* patt= prm + 99072;
    float* pcb = prm + 99456;
    float* pW1 = prm + 99840;
    float* pb1 = prm + 103936;
    float* pW2 = prm + 103968;
    float* pb2 = prm + 104480;
    float* pW3 = prm + 104496;
    float* pb3 = prm + 104688;

    // 1. zero degree histogram + fill counters (adjacent: 2N+1 ints)
    hipMemsetAsync(off, 0, (size_t)(2 * N_NODES + 1) * sizeof(int), stream);

    // 2. fused front-end: edge convert + histogram, param convert, weight swizzle
    k_prep<<<(P_TOT + 255) / 256, 256, 0, stream>>>(
        d_in[1], d_in[3], d_in[4], d_in[5], d_in[6], d_in[7], d_in[8],
        d_in[9], d_in[10], d_in[11], d_in[12], d_in[13], d_in[14],
        eidx, off, prm, wswz);

    // 3. CSR: 2-stage scan, then scatter
    k_scan1<<<NCHUNK, 1024, 0, stream>>>(off, part);
    k_scan3<<<NCHUNK, 1024, 0, stream>>>(off, part);
    k_scatter<<<(EA + 255) / 256, 256, 0, stream>>>(eidx, off, fill, csr);

    // 4. three GATv2 layers; h bf16-packed between conv layers (bit-exact:
    //    GEMM staging rounds to bf16 anyway), fp32 for the MLP input.
    //    k_attn: one wave per (node, head); heads contiguous in dispatch order.
    for (int i = 0; i < 3; i++) {
        k_gemm_mfma<<<(N_NODES + GM - 1) / GM, 256, 0, stream>>>(
            i == 0 ? (const void*)d_in[0] : (const void*)h,
            d_in[3], d_in[1], i == 0 ? 1 : 0,
            wswz + (long)i * WSWZ_L, pbl + (long)i * HC, pbr + (long)i * HC,
            xlbf, xr);
        k_attn<<<(N_NODES * HEADS) / 4, 256, 0, stream>>>(
            xlbf, xr, off, csr, patt + (long)i * HEADS * DIM, pcb + (long)i * HC,
            (void*)h, i < 2 ? 1 : 0);
    }

    // 5. fused MLP head
    k_mlp<<<(N_NODES + 15) / 16, 256, 0, stream>>>(h, pW1, pb1, pW2, pb2, h3);

    // 6. fused outputs (2 threads per edge; grid exactly covers 2*E)
    k_out<<<(2 * E_EDGES + 255) / 256, 256, 0, stream>>>(h3, eidx, pW3, pb3, d_out,
                                                         d_in[3], d_in[1]);
}

// Round 7
// 632.926 us; speedup vs baseline: 1.2914x; 1.2914x over previous
//
#include <hip/hip_runtime.h>
#include <hip/hip_bf16.h>

typedef __hip_bfloat16 bf16;
typedef __attribute__((ext_vector_type(8))) short bf16x8;
typedef __attribute__((ext_vector_type(4))) float f32x4;

#define N_NODES 50000
#define E_EDGES 800000
#define EA (E_EDGES + N_NODES)   // 850000 edges incl self-loops
#define HC 128                   // heads*dim
#define HEADS 4
#define DIM 32
#define DIM2 16
#define NCLS 6
#define SLOPE 0.2f
#define XN (N_NODES * HC)
#define GM 64                    // nodes per GEMM block (4 row-tiles/wave)
#define HSTRIDE 152              // padded ushort stride (304B)
#define WSWZ_L 32768             // swizzled weight ushorts per layer (256*128)
#define NCHUNK ((N_NODES + 1023) / 1024)   // 49

#define P_CVTI (2 * E_EDGES)     // 1,600,000
#define P_PRM  6390              // params after Wl/Wr (j in [98304,104694))
#define P_WSWZ (3 * WSWZ_L)      // 98,304
#define P_TOT  (P_CVTI + P_PRM + P_WSWZ)

__device__ __forceinline__ float b2f(bf16 v) { return __bfloat162float(v); }
__device__ __forceinline__ unsigned short f2bfu(float f) {
    bf16 b = __float2bfloat16(f);
    return *(unsigned short*)&b;
}
__device__ __forceinline__ unsigned packbf(float a, float b) {
    return (unsigned)f2bfu(a) | ((unsigned)f2bfu(b) << 16);
}

// ---- per-block inline dtype detector (reads ~6KB, L2-hot, deterministic) ----
// isf32: float tensors are fp32 (else bf16). is64: edge_index is int64.
__device__ __forceinline__ void block_detect(const void* wptr, const void* eptr,
                                             int* det, int& isf32, int& is64) {
    int tid = threadIdx.x;            // blockDim.x == 256
    if (tid == 0) { det[0] = 0; det[1] = 0; }
    __syncthreads();
    const unsigned short* w = (const unsigned short*)wptr;
    int badf = 0;
    for (int i = tid; i < 1024; i += 256) {
        unsigned v = w[i];
        unsigned ex = (v >> 7) & 0xFF;
        if (v != 0 && (ex < 90 || ex > 150)) badf++;
    }
    const int* ei = (const int*)eptr;
    int nz = 0;
    for (int i = tid; i < 1024; i += 256) {
        if (ei[2 * i + 1] != 0) nz++;
    }
    if (badf) atomicAdd(&det[0], badf);
    if (nz)   atomicAdd(&det[1], nz);
    __syncthreads();
    isf32 = det[0] > 100;   // fp32: ~390 expected; bf16: ~0
    is64  = det[1] < 100;   // int64: high words all 0; int32: ~512 nonzero
}

// ---- fused front-end: edge cvt + degree histogram, param cvt, weight swizzle --
__global__ __launch_bounds__(256) void k_prep(
        const void* eraw, const void* sWl, const void* sWr,
        const void* sbl, const void* sbr, const void* satt, const void* scb,
        const void* sW1, const void* sb1, const void* sW2, const void* sb2,
        const void* sW3, const void* sb3,
        int* __restrict__ eidx, int* __restrict__ off,
        float* __restrict__ prm, unsigned short* __restrict__ wswz) {
    __shared__ int det[2];
    int isf32, is64;
    block_detect(sWl, eraw, det, isf32, is64);

    int i = blockIdx.x * 256 + threadIdx.x;
    if (i < P_CVTI) {
        int v = is64 ? (int)((const long long*)eraw)[i] : ((const int*)eraw)[i];
        if (v < 0) v = 0;
        if (v >= N_NODES) v = N_NODES - 1;
        eidx[i] = v;
        if (i >= E_EDGES) atomicAdd(&off[v], 1);   // dst histogram (real edges)
        return;
    }
    i -= P_CVTI;
    if (i < P_PRM) {
        int j = i + 98304;
        const void* src; float* dst; int o;
        if      (j < 98688)  { src = sbl;  dst = prm + 98304;  o = j - 98304; }
        else if (j < 99072)  { src = sbr;  dst = prm + 98688;  o = j - 98688; }
        else if (j < 99456)  { src = satt; dst = prm + 99072;  o = j - 99072; }
        else if (j < 99840)  { src = scb;  dst = prm + 99456;  o = j - 99456; }
        else if (j < 103936) { src = sW1;  dst = prm + 99840;  o = j - 99840; }
        else if (j < 103968) { src = sb1;  dst = prm + 103936; o = j - 103936; }
        else if (j < 104480) { src = sW2;  dst = prm + 103968; o = j - 103968; }
        else if (j < 104496) { src = sb2;  dst = prm + 104480; o = j - 104480; }
        else if (j < 104688) { src = sW3;  dst = prm + 104496; o = j - 104496; }
        else                 { src = sb3;  dst = prm + 104688; o = j - 104688; }
        dst[o] = isf32 ? ((const float*)src)[o] : b2f(((const bf16*)src)[o]);
        return;
    }
    i -= P_PRM;
    if (i >= P_WSWZ) return;
    // weight swizzle straight from raw Wl/Wr (dtype branch)
    int L = i / WSWZ_L;
    int e = i % WSWZ_L;
    int ntile = e >> 11;
    int r2 = e & 2047;
    int ks = r2 >> 9;
    int r3 = r2 & 511;
    int lane = r3 >> 3;
    int j = r3 & 7;
    int col = ntile * 16 + (lane & 15);       // 0..255 combined (Wl | Wr)
    int k = ks * 32 + (lane >> 4) * 8 + j;
    const void* src = (col < HC) ? sWl : sWr;
    int idx = L * HC * HC + k * HC + (col & (HC - 1));
    float v = isf32 ? ((const float*)src)[idx] : b2f(((const bf16*)src)[idx]);
    wswz[i] = f2bfu(v);
}

// ---- parallel scan: stage 1 (block-local, incl +1 self-loop per node) ----
__global__ __launch_bounds__(1024) void k_scan1(int* __restrict__ off, int* __restrict__ part) {
    __shared__ int s[1024];
    int tid = threadIdx.x;
    int i = blockIdx.x * 1024 + tid;
    int v = (i < N_NODES) ? off[i] + 1 : 0;     // +1: self-loop
    s[tid] = v;
    __syncthreads();
    for (int o = 1; o < 1024; o <<= 1) {
        int t = (tid >= o) ? s[tid - o] : 0;
        __syncthreads();
        s[tid] += t;
        __syncthreads();
    }
    if (i < N_NODES) off[i] = s[tid] - v;       // exclusive
    if (tid == 1023) part[blockIdx.x] = s[1023];
}

// ---- stage 2: per-block wave-reduce of preceding chunk totals, then add ----
__global__ __launch_bounds__(1024) void k_scan3(int* __restrict__ off, const int* __restrict__ part) {
    __shared__ int sbase;
    int tid = threadIdx.x;
    if (tid < 64) {
        int v = (tid < NCHUNK && tid < (int)blockIdx.x) ? part[tid] : 0;
        for (int o = 32; o > 0; o >>= 1) v += __shfl_down(v, o);
        if (tid == 0) sbase = v;
    }
    __syncthreads();
    int i = blockIdx.x * 1024 + tid;
    if (i < N_NODES) off[i] += sbase;
    if (i == 0) off[N_NODES] = EA;
}

__global__ void k_scatter(const int* __restrict__ eidx, const int* __restrict__ off,
                          int* __restrict__ fill, int* __restrict__ csrsrc) {
    int e = blockIdx.x * blockDim.x + threadIdx.x;
    if (e >= EA) return;
    int src, dst;
    if (e < E_EDGES) { src = eidx[e]; dst = eidx[E_EDGES + e]; }
    else             { src = dst = e - E_EDGES; }
    int pos = off[dst] + atomicAdd(&fill[dst], 1);
    if (pos >= 0 && pos < EA) csrsrc[pos] = src;
}

// ------- MFMA GEMM (GM=64): xl(bf16-packed, node-major) cols 0..127, ----------
// ------- xr(fp32) cols 128..255. 4 row-tiles per wave -> weights read ---------
// ------- once per 64 nodes (half the L2 weight traffic of GM=32). -------------
__global__ __launch_bounds__(256) void k_gemm_mfma(
        const void* __restrict__ hsrc, const void* wdet, const void* edet,
        int detect_in,
        const unsigned short* __restrict__ wswz,
        const float* __restrict__ bl, const float* __restrict__ br,
        unsigned* __restrict__ xlbf, float* __restrict__ xr) {
    __shared__ unsigned short hs[GM * HSTRIDE];   // 19456 B
    __shared__ int det[2];
    int tid = threadIdx.x;
    int wave = tid >> 6, lane = tid & 63;
    long row0 = (long)blockIdx.x * GM;

    int f32in = 0;
    if (detect_in) {
        int is64d;
        block_detect(wdet, edet, det, f32in, is64d);
    }

    if (f32in) {
        for (int idx = tid; idx < GM * 64; idx += 256) {
            int r = idx >> 6, cp = idx & 63;
            float v0 = 0.f, v1 = 0.f;
            if (row0 + r < N_NODES) {
                const float2 hv = ((const float2*)((const float*)hsrc + (row0 + r) * HC))[cp];
                v0 = hv.x; v1 = hv.y;
            }
            *(unsigned*)&hs[r * HSTRIDE + cp * 2] = packbf(v0, v1);
        }
    } else {
        for (int idx = tid; idx < GM * 64; idx += 256) {
            int r = idx >> 6, cp = idx & 63;
            unsigned u = 0;
            if (row0 + r < N_NODES)
                u = ((const unsigned*)hsrc)[(row0 + r) * (HC / 2) + cp];
            *(unsigned*)&hs[r * HSTRIDE + cp * 2] = u;
        }
    }
    __syncthreads();

    int q = lane >> 4, l16 = lane & 15;
    for (int nt = 0; nt < 4; nt++) {
        int colbase = wave * 64 + nt * 16;
        int col = colbase + l16;          // 0..255 combined
        int ntile = colbase >> 4;
        f32x4 acc0 = {0.f, 0.f, 0.f, 0.f};
        f32x4 acc1 = {0.f, 0.f, 0.f, 0.f};
        f32x4 acc2 = {0.f, 0.f, 0.f, 0.f};
        f32x4 acc3 = {0.f, 0.f, 0.f, 0.f};
#pragma unroll
        for (int ks = 0; ks < 4; ks++) {
            bf16x8 bfrag = *(const bf16x8*)(wswz + (((ntile * 4 + ks) * 64 + lane) << 3));
            int ko = ks * 32 + q * 8;
            bf16x8 a0 = *(const bf16x8*)(hs + l16 * HSTRIDE + ko);
            bf16x8 a1 = *(const bf16x8*)(hs + (16 + l16) * HSTRIDE + ko);
            bf16x8 a2 = *(const bf16x8*)(hs + (32 + l16) * HSTRIDE + ko);
            bf16x8 a3 = *(const bf16x8*)(hs + (48 + l16) * HSTRIDE + ko);
            acc0 = __builtin_amdgcn_mfma_f32_16x16x32_bf16(a0, bfrag, acc0, 0, 0, 0);
            acc1 = __builtin_amdgcn_mfma_f32_16x16x32_bf16(a1, bfrag, acc1, 0, 0, 0);
            acc2 = __builtin_amdgcn_mfma_f32_16x16x32_bf16(a2, bfrag, acc2, 0, 0, 0);
            acc3 = __builtin_amdgcn_mfma_f32_16x16x32_bf16(a3, bfrag, acc3, 0, 0, 0);
        }
        if (col < HC) {
            float bias = bl[col];
            int cp = col >> 1;
#pragma unroll
            for (int reg = 0; reg < 4; reg++) {
                float v0 = acc0[reg] + bias;
                float v1 = acc1[reg] + bias;
                float v2 = acc2[reg] + bias;
                float v3 = acc3[reg] + bias;
                float p0 = __shfl_xor(v0, 1);
                float p1 = __shfl_xor(v1, 1);
                float p2 = __shfl_xor(v2, 1);
                float p3 = __shfl_xor(v3, 1);
                if ((lane & 1) == 0) {
                    long n0 = row0 + q * 4 + reg;
                    long n1 = row0 + 16 + q * 4 + reg;
                    long n2 = row0 + 32 + q * 4 + reg;
                    long n3 = row0 + 48 + q * 4 + reg;
                    if (n0 < N_NODES) xlbf[n0 * (HC / 2) + cp] = packbf(v0, p0);
                    if (n1 < N_NODES) xlbf[n1 * (HC / 2) + cp] = packbf(v1, p1);
                    if (n2 < N_NODES) xlbf[n2 * (HC / 2) + cp] = packbf(v2, p2);
                    if (n3 < N_NODES) xlbf[n3 * (HC / 2) + cp] = packbf(v3, p3);
                }
            }
        } else {
            int c = col - HC;
            float bias = br[c];
#pragma unroll
            for (int reg = 0; reg < 4; reg++) {
                long n0 = row0 + q * 4 + reg;
                long n1 = row0 + 16 + q * 4 + reg;
                long n2 = row0 + 32 + q * 4 + reg;
                long n3 = row0 + 48 + q * 4 + reg;
                if (n0 < N_NODES) xr[n0 * HC + c] = acc0[reg] + bias;
                if (n1 < N_NODES) xr[n1 * HC + c] = acc1[reg] + bias;
                if (n2 < N_NODES) xr[n2 * HC + c] = acc2[reg] + bias;
                if (n3 < N_NODES) xr[n3 * HC + c] = acc3[reg] + bias;
            }
        }
    }
}

// --- GATv2 aggregation: 16 lanes/edge, depth-4 gather pipeline, flash merge ---
// Index staged 1 iter ahead of its gather; gather issued 4 iters ahead of use.
// out_bf16: write packed bf16 h (consumed by next gemm), else fp32 (for MLP)
__global__ __launch_bounds__(256) void k_attn(
        const unsigned* __restrict__ xlbf, const float* __restrict__ xr,
        const int* __restrict__ off, const int* __restrict__ csrsrc,
        const float* __restrict__ att, const float* __restrict__ cb,
        void* __restrict__ hout, int out_bf16) {
    int wave = threadIdx.x >> 6;
    int lane = threadIdx.x & 63;
    int node = blockIdx.x * 4 + wave;
    if (node >= N_NODES) return;
    int grp = lane >> 4;
    int gl  = lane & 15;
    int fb  = gl * 8;
    int head = fb >> 5;

    const float4* xrp = (const float4*)(xr + (long)node * HC + fb);
    float4 xa = xrp[0], xb = xrp[1];
    const float4* ap = (const float4*)(att + head * DIM + (fb & 31));
    float4 aa = ap[0], ab = ap[1];

    int e0 = off[node], e1 = off[node + 1];
    if (e0 < 0) e0 = 0;
    if (e1 > EA) e1 = EA;
    if (e1 <= e0) {
        if (grp == 0) {
            if (out_bf16) {
                uint4 z = {0u, 0u, 0u, 0u};
                *(uint4*)((unsigned*)hout + (long)node * (HC / 2) + gl * 4) = z;
            } else {
                float4 z = make_float4(0.f, 0.f, 0.f, 0.f);
                ((float4*)((float*)hout + (long)node * HC + fb))[0] = z;
                ((float4*)((float*)hout + (long)node * HC + fb))[1] = z;
            }
        }
        return;
    }
    int klast = e1 - 1;
    const char* xlb = (const char*)xlbf;
    unsigned glo = (unsigned)gl * 16u;
#define XLD(s) (*(const uint4*)(xlb + (((unsigned)(s) << 8) + glo)))
#define CLMP(x) ((x) < klast ? (x) : klast)

    int k0 = e0 + grp;
    int sa = csrsrc[CLMP(k0)];
    int sb = csrsrc[CLMP(k0 + 4)];
    int sc = csrsrc[CLMP(k0 + 8)];
    int sd = csrsrc[CLMP(k0 + 12)];
    int sP = csrsrc[CLMP(k0 + 16)];
    uint4 u0 = XLD(sa);
    uint4 u1 = XLD(sb);
    uint4 u2 = XLD(sc);
    uint4 u3 = XLD(sd);

    float m = -1e30f, ssum = 0.f;
    float acc[8];
#pragma unroll
    for (int j = 0; j < 8; j++) acc[j] = 0.f;

    for (int kk = k0; kk < e1; kk += 4) {
        uint4 cur = u0;
        u0 = u1; u1 = u2; u2 = u3;
        u3 = XLD(sP);                     // edge kk+16 (index loaded last iter)
        sP = csrsrc[CLMP(kk + 20)];       // index for next iter's gather

        float x0 = __uint_as_float(cur.x << 16);
        float x1 = __uint_as_float(cur.x & 0xffff0000u);
        float x2 = __uint_as_float(cur.y << 16);
        float x3 = __uint_as_float(cur.y & 0xffff0000u);
        float x4 = __uint_as_float(cur.z << 16);
        float x5 = __uint_as_float(cur.z & 0xffff0000u);
        float x6 = __uint_as_float(cur.w << 16);
        float x7 = __uint_as_float(cur.w & 0xffff0000u);
        float m0 = x0 + xa.x, m1 = x1 + xa.y, m2 = x2 + xa.z, m3 = x3 + xa.w;
        float m4 = x4 + xb.x, m5 = x5 + xb.y, m6 = x6 + xb.z, m7 = x7 + xb.w;
        float l0 = fmaxf(m0, SLOPE * m0), l1 = fmaxf(m1, SLOPE * m1);
        float l2 = fmaxf(m2, SLOPE * m2), l3 = fmaxf(m3, SLOPE * m3);
        float l4 = fmaxf(m4, SLOPE * m4), l5 = fmaxf(m5, SLOPE * m5);
        float l6 = fmaxf(m6, SLOPE * m6), l7 = fmaxf(m7, SLOPE * m7);
        float p = l0 * aa.x + l1 * aa.y + l2 * aa.z + l3 * aa.w
                + l4 * ab.x + l5 * ab.y + l6 * ab.z + l7 * ab.w;
        p += __shfl_xor(p, 1);
        p += __shfl_xor(p, 2);
        float mn = fmaxf(m, p);
        float sc_ = __expf(m - mn);
        float ex = __expf(p - mn);
        ssum = ssum * sc_ + ex;
        acc[0] = acc[0] * sc_ + ex * x0;
        acc[1] = acc[1] * sc_ + ex * x1;
        acc[2] = acc[2] * sc_ + ex * x2;
        acc[3] = acc[3] * sc_ + ex * x3;
        acc[4] = acc[4] * sc_ + ex * x4;
        acc[5] = acc[5] * sc_ + ex * x5;
        acc[6] = acc[6] * sc_ + ex * x6;
        acc[7] = acc[7] * sc_ + ex * x7;
        m = mn;
    }
#undef XLD
#undef CLMP

#pragma unroll
    for (int d = 16; d <= 32; d <<= 1) {
        float mo = __shfl_xor(m, d);
        float so = __shfl_xor(ssum, d);
        float ao[8];
#pragma unroll
        for (int j = 0; j < 8; j++) ao[j] = __shfl_xor(acc[j], d);
        float mn = fmaxf(m, mo);
        float s1f = __expf(m - mn);
        float s2f = __expf(mo - mn);
        ssum = ssum * s1f + so * s2f;
#pragma unroll
        for (int j = 0; j < 8; j++) acc[j] = acc[j] * s1f + ao[j] * s2f;
        m = mn;
    }

    if (grp == 0) {
        float inv = 1.f / (ssum + 1e-16f);
        const float4* cbp = (const float4*)(cb + fb);
        float4 c0 = cbp[0], c1 = cbp[1];
        float o0 = fmaxf(acc[0] * inv + c0.x, 0.f);
        float o1 = fmaxf(acc[1] * inv + c0.y, 0.f);
        float o2 = fmaxf(acc[2] * inv + c0.z, 0.f);
        float o3 = fmaxf(acc[3] * inv + c0.w, 0.f);
        float o4 = fmaxf(acc[4] * inv + c1.x, 0.f);
        float o5 = fmaxf(acc[5] * inv + c1.y, 0.f);
        float o6 = fmaxf(acc[6] * inv + c1.z, 0.f);
        float o7 = fmaxf(acc[7] * inv + c1.w, 0.f);
        if (out_bf16) {
            uint4 w;
            w.x = packbf(o0, o1);
            w.y = packbf(o2, o3);
            w.z = packbf(o4, o5);
            w.w = packbf(o6, o7);
            *(uint4*)((unsigned*)hout + (long)node * (HC / 2) + gl * 4) = w;
        } else {
            float4 a0 = make_float4(o0, o1, o2, o3);
            float4 a1 = make_float4(o4, o5, o6, o7);
            float4* op = (float4*)((float*)hout + (long)node * HC + fb);
            op[0] = a0;
            op[1] = a1;
        }
    }
}

// ---- fused MLP head: h3 = relu(relu(h @ W1 + b1) @ W2 + b2), 16 nodes/block --
__global__ __launch_bounds__(256) void k_mlp(
        const float* __restrict__ h, const float* __restrict__ W1,
        const float* __restrict__ b1, const float* __restrict__ W2,
        const float* __restrict__ b2, float* __restrict__ h3) {
    __shared__ float w1s[HC * DIM];       // 16 KB
    __shared__ float hs[16 * HC];         // 8 KB
    __shared__ float h2s[16 * DIM];       // 2 KB
    __shared__ float w2s[DIM * DIM2];     // 2 KB
    int tid = threadIdx.x;
    long row0 = (long)blockIdx.x * 16;
    for (int idx = tid; idx < HC * DIM; idx += 256) w1s[idx] = W1[idx];
    for (int idx = tid; idx < DIM * DIM2; idx += 256) w2s[idx] = W2[idx];
    for (int idx = tid; idx < 16 * HC; idx += 256) {
        long g = row0 * HC + idx;
        hs[idx] = (g < (long)N_NODES * HC) ? h[g] : 0.f;
    }
    __syncthreads();
#pragma unroll
    for (int p = 0; p < 2; p++) {
        int idx = tid + p * 256;
        int r = idx >> 5, c = idx & 31;
        float acc = b1[c];
        for (int k = 0; k < HC; k++) acc += hs[r * HC + k] * w1s[k * DIM + c];
        h2s[r * DIM + c] = acc > 0.f ? acc : 0.f;
    }
    __syncthreads();
    int r = tid >> 4, c = tid & 15;
    float acc = b2[c];
    for (int k = 0; k < DIM; k++) acc += h2s[r * DIM + k] * w2s[k * DIM2 + c];
    long row = row0 + r;
    if (row < N_NODES) h3[row * DIM2 + c] = acc > 0.f ? acc : 0.f;
}

// --- fused head, 2 threads/edge: pair (even=src, odd=dst) each gathers one ---
// --- h3 row (64B contiguous), stores its eout half; out0 via shfl_xor(1).  ---
__global__ __launch_bounds__(256) void k_out(
        const float* __restrict__ h3, const int* __restrict__ eidx,
        const float* __restrict__ W3, const float* __restrict__ b3,
        void* __restrict__ dout, const void* wdet, const void* edet) {
    __shared__ float w3s[2 * DIM2 * NCLS];
    __shared__ float bs[NCLS];
    __shared__ int det[2];
    int isf32, is64d;
    block_detect(wdet, edet, det, isf32, is64d);
    int tid = threadIdx.x;
    if (tid < 2 * DIM2 * NCLS) w3s[tid] = W3[tid];
    if (tid < NCLS) bs[tid] = b3[tid];
    __syncthreads();
    int idx = blockIdx.x * 256 + tid;     // grid covers exactly 2*E threads
    int e = idx >> 1, half = idx & 1;
    int node = eidx[half * E_EDGES + e];
    float4 t0, t1, t2, t3;
    {
        const float4* ps = (const float4*)(h3 + (long)node * DIM2);
        t0 = ps[0]; t1 = ps[1]; t2 = ps[2]; t3 = ps[3];
    }
    float v[DIM2];
    v[0] = t0.x;  v[1] = t0.y;  v[2] = t0.z;  v[3] = t0.w;
    v[4] = t1.x;  v[5] = t1.y;  v[6] = t1.z;  v[7] = t1.w;
    v[8] = t2.x;  v[9] = t2.y;  v[10] = t2.z; v[11] = t2.w;
    v[12] = t3.x; v[13] = t3.y; v[14] = t3.z; v[15] = t3.w;
    const float* wrow = w3s + half * DIM2 * NCLS;
    float o[NCLS];
#pragma unroll
    for (int j = 0; j < NCLS; j++) {
        float acc = half ? 0.f : bs[j];
#pragma unroll
        for (int k = 0; k < DIM2; k++) acc += v[k] * wrow[k * NCLS + j];
        o[j] = acc;
    }
#pragma unroll
    for (int j = 0; j < NCLS; j++) o[j] += __shfl_xor(o[j], 1);
    if (isf32) {
        float4* eo = (float4*)((float*)dout + (long)E_EDGES * NCLS
                               + (long)e * 32 + half * 16);
        eo[0] = t0; eo[1] = t1; eo[2] = t2; eo[3] = t3;
        if (!half) {
            float2* out0 = (float2*)dout;
            out0[(long)e * 3 + 0] = make_float2(o[0], o[1]);
            out0[(long)e * 3 + 1] = make_float2(o[2], o[3]);
            out0[(long)e * 3 + 2] = make_float2(o[4], o[5]);
        }
    } else {
        uint4 wa, wb;
        wa.x = packbf(v[0], v[1]);   wa.y = packbf(v[2], v[3]);
        wa.z = packbf(v[4], v[5]);   wa.w = packbf(v[6], v[7]);
        wb.x = packbf(v[8], v[9]);   wb.y = packbf(v[10], v[11]);
        wb.z = packbf(v[12], v[13]); wb.w = packbf(v[14], v[15]);
        uint4* eo = (uint4*)((bf16*)dout + (long)E_EDGES * NCLS)
                    + (long)e * 4 + half * 2;
        eo[0] = wa; eo[1] = wb;
        if (!half) {
            unsigned* out0 = (unsigned*)dout;
            out0[(long)e * 3 + 0] = packbf(o[0], o[1]);
            out0[(long)e * 3 + 1] = packbf(o[2], o[3]);
            out0[(long)e * 3 + 2] = packbf(o[4], o[5]);
        }
    }
}

extern "C" void kernel_launch(void* const* d_in, const int* in_sizes, int n_in,
                              void* d_out, int out_size, void* d_ws, size_t ws_size,
                              hipStream_t stream) {
    // ---- workspace layout (4-byte word offsets) ----
    float* wsf   = (float*)d_ws;
    float* h     = wsf + 16;                       // bf16-packed h layers 0-1; fp32 last
    float* xl    = h  + (long)N_NODES * HC;        // xlbf overlay; h3 overlay post-conv
    float* xr    = xl + (long)N_NODES * HC;
    float* prm   = xr + (long)N_NODES * HC;        // 110,000 (Wl/Wr slots unused)
    unsigned short* wswz = (unsigned short*)(prm + 110000);  // 3*32768 ushorts
    int*   eidx  = (int*)(wswz + P_WSWZ);          // 1,600,000
    int*   off   = eidx + 2 * E_EDGES;             // 50,001
    int*   fill  = off + (N_NODES + 1);            // 50,000
    int*   csr   = fill + N_NODES;                 // 850,000
    int*   part  = csr + EA;                       // 64
    unsigned* xlbf = (unsigned*)xl;                // node-major: N*64 packed bf16x2
    float* h3 = xl;                                // overlay (free after last attn)

    float* pbl = prm + 98304;
    float* pbr = prm + 98688;
    float* patt= prm + 99072;
    float* pcb = prm + 99456;
    float* pW1 = prm + 99840;
    float* pb1 = prm + 103936;
    float* pW2 = prm + 103968;
    float* pb2 = prm + 104480;
    float* pW3 = prm + 104496;
    float* pb3 = prm + 104688;

    // 1. zero degree histogram + fill counters (adjacent: 2N+1 ints)
    hipMemsetAsync(off, 0, (size_t)(2 * N_NODES + 1) * sizeof(int), stream);

    // 2. fused front-end: edge convert + histogram, param convert, weight swizzle
    k_prep<<<(P_TOT + 255) / 256, 256, 0, stream>>>(
        d_in[1], d_in[3], d_in[4], d_in[5], d_in[6], d_in[7], d_in[8],
        d_in[9], d_in[10], d_in[11], d_in[12], d_in[13], d_in[14],
        eidx, off, prm, wswz);

    // 3. CSR: 2-stage scan, then scatter
    k_scan1<<<NCHUNK, 1024, 0, stream>>>(off, part);
    k_scan3<<<NCHUNK, 1024, 0, stream>>>(off, part);
    k_scatter<<<(EA + 255) / 256, 256, 0, stream>>>(eidx, off, fill, csr);

    // 4. three GATv2 layers; h bf16-packed between conv layers (bit-exact:
    //    GEMM staging rounds to bf16 anyway), fp32 for the MLP input.
    for (int i = 0; i < 3; i++) {
        k_gemm_mfma<<<(N_NODES + GM - 1) / GM, 256, 0, stream>>>(
            i == 0 ? (const void*)d_in[0] : (const void*)h,
            d_in[3], d_in[1], i == 0 ? 1 : 0,
            wswz + (long)i * WSWZ_L, pbl + (long)i * HC, pbr + (long)i * HC,
            xlbf, xr);
        k_attn<<<(N_NODES + 3) / 4, 256, 0, stream>>>(
            xlbf, xr, off, csr, patt + (long)i * HEADS * DIM, pcb + (long)i * HC,
            (void*)h, i < 2 ? 1 : 0);
    }

    // 5. fused MLP head
    k_mlp<<<(N_NODES + 15) / 16, 256, 0, stream>>>(h, pW1, pb1, pW2, pb2, h3);

    // 6. fused outputs (2 threads per edge; grid exactly covers 2*E)
    k_out<<<(2 * E_EDGES + 255) / 256, 256, 0, stream>>>(h3, eidx, pW3, pb3, d_out,
                                                         d_in[3], d_in[1]);
}

// Round 8
// 561.245 us; speedup vs baseline: 1.4564x; 1.1277x over previous
//
#include <hip/hip_runtime.h>
#include <hip/hip_bf16.h>

typedef __hip_bfloat16 bf16;
typedef __attribute__((ext_vector_type(8))) short bf16x8;
typedef __attribute__((ext_vector_type(4))) float f32x4;

#define N_NODES 50000
#define E_EDGES 800000
#define EA (E_EDGES + N_NODES)   // 850000 edges incl self-loops
#define HC 128                   // heads*dim
#define HEADS 4
#define DIM 32
#define DIM2 16
#define NCLS 6
#define SLOPE 0.2f
#define NCHUNK ((N_NODES + 1023) / 1024)   // 49
#define XN (N_NODES * HC)                  // 6,400,000
#define GM 32                              // nodes per GEMM block
#define HSTRIDE 152                        // padded ushort stride (304B: 16B-aligned, 2-way banks)
#define WSWZ_L 32768                       // swizzled weight ushorts per layer (256*128)

__device__ __forceinline__ float b2f(bf16 v) { return __bfloat162float(v); }
__device__ __forceinline__ unsigned short f2bfu(float f) {
    bf16 b = __float2bfloat16(f);
    return *(unsigned short*)&b;
}

// ---------------- dtype detector ----------------
// flags[0]=1 -> float inputs (and output) are fp32; 0 -> bf16
// flags[1]=1 -> edge_index is int64; 0 -> int32
__global__ __launch_bounds__(256) void k_detect(const void* wptr, const void* eptr,
                                                int* __restrict__ flags) {
    __shared__ int sb[256], sn[256];
    int tid = threadIdx.x;
    const unsigned short* w = (const unsigned short*)wptr;
    int badf = 0;
    for (int i = tid; i < 4096; i += 256) {
        unsigned v = w[i];
        unsigned ex = (v >> 7) & 0xFF;
        if (v != 0 && (ex < 90 || ex > 150)) badf++;
    }
    const int* ei = (const int*)eptr;
    int nz = 0;
    for (int i = tid; i < 2048; i += 256) {
        if (ei[2 * i + 1] != 0) nz++;
    }
    sb[tid] = badf; sn[tid] = nz;
    __syncthreads();
    for (int ofs = 128; ofs > 0; ofs >>= 1) {
        if (tid < ofs) { sb[tid] += sb[tid + ofs]; sn[tid] += sn[tid + ofs]; }
        __syncthreads();
    }
    if (tid == 0) {
        flags[0] = (sb[0] > 64) ? 1 : 0;
        flags[1] = (sn[0] < 64) ? 1 : 0;
    }
}

// ---------- single fused conversion of x + all params to fp32 scratch ----------
__global__ void k_cvt_all(const void* sx, const void* sWl, const void* sWr,
                          const void* sbl, const void* sbr, const void* satt,
                          const void* scb, const void* sW1, const void* sb1,
                          const void* sW2, const void* sb2, const void* sW3,
                          const void* sb3,
                          float* __restrict__ h, float* __restrict__ prm,
                          const int* __restrict__ flags) {
    int i = blockIdx.x * blockDim.x + threadIdx.x;
    if (i >= XN + 104694) return;
    const void* src; float* dst; int off;
    if (i < XN) { src = sx; dst = h; off = i; }
    else {
        int j = i - XN;
        if      (j < 49152)  { src = sWl;  dst = prm;           off = j; }
        else if (j < 98304)  { src = sWr;  dst = prm + 49152;   off = j - 49152; }
        else if (j < 98688)  { src = sbl;  dst = prm + 98304;   off = j - 98304; }
        else if (j < 99072)  { src = sbr;  dst = prm + 98688;   off = j - 98688; }
        else if (j < 99456)  { src = satt; dst = prm + 99072;   off = j - 99072; }
        else if (j < 99840)  { src = scb;  dst = prm + 99456;   off = j - 99456; }
        else if (j < 103936) { src = sW1;  dst = prm + 99840;   off = j - 99840; }
        else if (j < 103968) { src = sb1;  dst = prm + 103936;  off = j - 103936; }
        else if (j < 104480) { src = sW2;  dst = prm + 103968;  off = j - 103968; }
        else if (j < 104496) { src = sb2;  dst = prm + 104480;  off = j - 104480; }
        else if (j < 104688) { src = sW3;  dst = prm + 104496;  off = j - 104496; }
        else                 { src = sb3;  dst = prm + 104688;  off = j - 104688; }
    }
    float v = flags[0] ? ((const float*)src)[off] : b2f(((const bf16*)src)[off]);
    dst[off] = v;
}

__global__ void k_cvti(const void* __restrict__ src, int* __restrict__ dst, int n,
                       const int* __restrict__ flags) {
    int i = blockIdx.x * blockDim.x + threadIdx.x;
    if (i >= n) return;
    int v;
    if (flags[1]) v = (int)((const long long*)src)[i];
    else          v = ((const int*)src)[i];
    if (v < 0) v = 0;
    if (v >= N_NODES) v = N_NODES - 1;
    dst[i] = v;
}

// ------- swizzle Wl/Wr (fp32) into MFMA B-fragment order, bf16 ----------------
// wswz[L][ntile][ks][lane][j]: col = ntile*16+(lane&15), k = ks*32+(lane>>4)*8+j
__global__ void k_wswz(const float* __restrict__ prm, unsigned short* __restrict__ wswz) {
    int i = blockIdx.x * blockDim.x + threadIdx.x;
    if (i >= 3 * WSWZ_L) return;
    int L = i / WSWZ_L;
    int e = i % WSWZ_L;
    int ntile = e >> 11;            // /2048
    int r2 = e & 2047;
    int ks = r2 >> 9;               // /512
    int r3 = r2 & 511;
    int lane = r3 >> 3;
    int j = r3 & 7;
    int col = ntile * 16 + (lane & 15);
    int k = ks * 32 + (lane >> 4) * 8 + j;
    float v;
    if (col < HC) v = prm[L * HC * HC + k * HC + col];                    // Wl
    else          v = prm[49152 + L * HC * HC + k * HC + (col - HC)];     // Wr
    wswz[i] = f2bfu(v);
}

// ---------------- CSR build ----------------
__global__ void k_zero(int* __restrict__ off, int* __restrict__ fill) {
    int i = blockIdx.x * blockDim.x + threadIdx.x;
    if (i <= N_NODES) off[i] = 0;
    if (i < N_NODES) fill[i] = 0;
}

__global__ void k_hist(const int* __restrict__ eidx, int* __restrict__ off) {
    int e = blockIdx.x * blockDim.x + threadIdx.x;
    if (e >= EA) return;
    int dst = (e < E_EDGES) ? eidx[E_EDGES + e] : (e - E_EDGES);
    atomicAdd(&off[dst], 1);
}

__global__ __launch_bounds__(1024) void k_scan1(int* __restrict__ off, int* __restrict__ part) {
    __shared__ int s[1024];
    int tid = threadIdx.x;
    int i = blockIdx.x * 1024 + tid;
    int v = (i < N_NODES) ? off[i] : 0;
    s[tid] = v;
    __syncthreads();
    for (int o = 1; o < 1024; o <<= 1) {
        int t = (tid >= o) ? s[tid - o] : 0;
        __syncthreads();
        s[tid] += t;
        __syncthreads();
    }
    if (i < N_NODES) off[i] = s[tid] - v;
    if (tid == 1023) part[blockIdx.x] = s[1023];
}

__global__ __launch_bounds__(64) void k_scan2(int* __restrict__ part) {
    int tid = threadIdx.x;
    int v = (tid < NCHUNK) ? part[tid] : 0;
    int orig = v;
    for (int o = 1; o < 64; o <<= 1) {
        int t = __shfl_up(v, o);
        if (tid >= o) v += t;
    }
    if (tid < NCHUNK) part[tid] = v - orig;
}

__global__ __launch_bounds__(1024) void k_scan3(int* __restrict__ off, const int* __restrict__ part) {
    int i = blockIdx.x * 1024 + threadIdx.x;
    if (i < N_NODES) off[i] += part[blockIdx.x];
    if (i == 0) off[N_NODES] = EA;
}

__global__ void k_scatter(const int* __restrict__ eidx, const int* __restrict__ off,
                          int* __restrict__ fill, int* __restrict__ csrsrc) {
    int e = blockIdx.x * blockDim.x + threadIdx.x;
    if (e >= EA) return;
    int src, dst;
    if (e < E_EDGES) { src = eidx[e]; dst = eidx[E_EDGES + e]; }
    else             { src = dst = e - E_EDGES; }
    int pos = off[dst] + atomicAdd(&fill[dst], 1);
    if (pos >= 0 && pos < EA) csrsrc[pos] = src;
}

// ------- MFMA GEMM: xl(bf16-packed) cols 0..127, xr(fp32) cols 128..255 --------
// block = 256 thr / 4 waves, 32 nodes; wave w owns 64 combined cols.
__global__ __launch_bounds__(256) void k_gemm_mfma(
        const float* __restrict__ h,
        const unsigned short* __restrict__ wswz,
        const float* __restrict__ bl, const float* __restrict__ br,
        unsigned* __restrict__ xlbf, float* __restrict__ xr) {
    __shared__ unsigned short hs[GM * HSTRIDE];   // 9728 B
    int tid = threadIdx.x;
    int wave = tid >> 6, lane = tid & 63;
    long row0 = (long)blockIdx.x * GM;

    // stage h tile as bf16 pairs into padded LDS
    for (int idx = tid; idx < GM * 64; idx += 256) {
        int r = idx >> 6, cp = idx & 63;
        float v0 = 0.f, v1 = 0.f;
        if (row0 + r < N_NODES) {
            const float2 hv = ((const float2*)(h + (row0 + r) * HC))[cp];
            v0 = hv.x; v1 = hv.y;
        }
        unsigned* dst = (unsigned*)&hs[r * HSTRIDE + cp * 2];
        *dst = (unsigned)f2bfu(v0) | ((unsigned)f2bfu(v1) << 16);
    }
    __syncthreads();

    int q = lane >> 4, l16 = lane & 15;
    for (int nt = 0; nt < 4; nt++) {
        int colbase = wave * 64 + nt * 16;
        int col = colbase + l16;          // 0..255 combined
        int ntile = colbase >> 4;
        f32x4 acc0 = {0.f, 0.f, 0.f, 0.f};
        f32x4 acc1 = {0.f, 0.f, 0.f, 0.f};
#pragma unroll
        for (int ks = 0; ks < 4; ks++) {
            bf16x8 bfrag = *(const bf16x8*)(wswz + (((ntile * 4 + ks) * 64 + lane) << 3));
            bf16x8 a0 = *(const bf16x8*)(hs + l16 * HSTRIDE + ks * 32 + q * 8);
            bf16x8 a1 = *(const bf16x8*)(hs + (16 + l16) * HSTRIDE + ks * 32 + q * 8);
            acc0 = __builtin_amdgcn_mfma_f32_16x16x32_bf16(a0, bfrag, acc0, 0, 0, 0);
            acc1 = __builtin_amdgcn_mfma_f32_16x16x32_bf16(a1, bfrag, acc1, 0, 0, 0);
        }
        // D: row = q*4+reg (within 16-node tile), col = l16
        if (col < HC) {
            float bias = bl[col];
#pragma unroll
            for (int reg = 0; reg < 4; reg++) {
                float v0 = acc0[reg] + bias;
                float v1 = acc1[reg] + bias;
                float p0 = __shfl_xor(v0, 1);
                float p1 = __shfl_xor(v1, 1);
                if ((lane & 1) == 0) {
                    long n0 = row0 + q * 4 + reg;
                    long n1 = row0 + 16 + q * 4 + reg;
                    unsigned u0 = (unsigned)f2bfu(v0) | ((unsigned)f2bfu(p0) << 16);
                    unsigned u1 = (unsigned)f2bfu(v1) | ((unsigned)f2bfu(p1) << 16);
                    int cp = col >> 1;
                    if (n0 < N_NODES) xlbf[n0 * (HC / 2) + cp] = u0;
                    if (n1 < N_NODES) xlbf[n1 * (HC / 2) + cp] = u1;
                }
            }
        } else {
            int c = col - HC;
            float bias = br[c];
#pragma unroll
            for (int reg = 0; reg < 4; reg++) {
                long n0 = row0 + q * 4 + reg;
                long n1 = row0 + 16 + q * 4 + reg;
                if (n0 < N_NODES) xr[n0 * HC + c] = acc0[reg] + bias;
                if (n1 < N_NODES) xr[n1 * HC + c] = acc1[reg] + bias;
            }
        }
    }
}

// --- GATv2 aggregation: 16 lanes/edge, 4 edges in flight/wave, flash merge ----
__global__ __launch_bounds__(256) void k_attn(
        const unsigned* __restrict__ xlbf, const float* __restrict__ xr,
        const int* __restrict__ off, const int* __restrict__ csrsrc,
        const float* __restrict__ att, const float* __restrict__ cb,
        float* __restrict__ hout) {
    int wave = threadIdx.x >> 6;
    int lane = threadIdx.x & 63;
    int node = blockIdx.x * 4 + wave;
    if (node >= N_NODES) return;
    int grp = lane >> 4;
    int gl  = lane & 15;
    int fb  = gl * 8;
    int head = fb >> 5;

    const float4* xrp = (const float4*)(xr + (long)node * HC + fb);
    float4 xa = xrp[0], xb = xrp[1];
    const float4* ap = (const float4*)(att + head * DIM + (fb & 31));
    float4 aa = ap[0], ab = ap[1];

    int e0 = off[node], e1 = off[node + 1];
    if (e0 < 0) e0 = 0;
    if (e1 > EA) e1 = EA;
    if (e1 <= e0) {
        if (grp == 0) {
            float4 z = make_float4(0.f, 0.f, 0.f, 0.f);
            ((float4*)(hout + (long)node * HC + fb))[0] = z;
            ((float4*)(hout + (long)node * HC + fb))[1] = z;
        }
        return;
    }
    int klast = e1 - 1;

    int k0 = e0 + grp;
    int ka = k0 < klast ? k0 : klast;
    int kb = (k0 + 4) < klast ? (k0 + 4) : klast;
    int sa = csrsrc[ka];
    int sb = csrsrc[kb];
    uint4 u0 = ((const uint4*)(xlbf + (long)sa * (HC / 2)))[gl];
    uint4 u1 = ((const uint4*)(xlbf + (long)sb * (HC / 2)))[gl];

    float m = -1e30f, ssum = 0.f;
    float acc[8];
#pragma unroll
    for (int j = 0; j < 8; j++) acc[j] = 0.f;

    for (int kk = k0; kk < e1; kk += 4) {
        uint4 cur = u0;
        u0 = u1;
        int kp = (kk + 8) < klast ? (kk + 8) : klast;
        int sp = csrsrc[kp];
        u1 = ((const uint4*)(xlbf + (long)sp * (HC / 2)))[gl];

        float x0 = __uint_as_float(cur.x << 16);
        float x1 = __uint_as_float(cur.x & 0xffff0000u);
        float x2 = __uint_as_float(cur.y << 16);
        float x3 = __uint_as_float(cur.y & 0xffff0000u);
        float x4 = __uint_as_float(cur.z << 16);
        float x5 = __uint_as_float(cur.z & 0xffff0000u);
        float x6 = __uint_as_float(cur.w << 16);
        float x7 = __uint_as_float(cur.w & 0xffff0000u);
        float m0 = x0 + xa.x, m1 = x1 + xa.y, m2 = x2 + xa.z, m3 = x3 + xa.w;
        float m4 = x4 + xb.x, m5 = x5 + xb.y, m6 = x6 + xb.z, m7 = x7 + xb.w;
        float l0 = fmaxf(m0, SLOPE * m0), l1 = fmaxf(m1, SLOPE * m1);
        float l2 = fmaxf(m2, SLOPE * m2), l3 = fmaxf(m3, SLOPE * m3);
        float l4 = fmaxf(m4, SLOPE * m4), l5 = fmaxf(m5, SLOPE * m5);
        float l6 = fmaxf(m6, SLOPE * m6), l7 = fmaxf(m7, SLOPE * m7);
        float p = l0 * aa.x + l1 * aa.y + l2 * aa.z + l3 * aa.w
                + l4 * ab.x + l5 * ab.y + l6 * ab.z + l7 * ab.w;
        p += __shfl_xor(p, 1);
        p += __shfl_xor(p, 2);
        float mn = fmaxf(m, p);
        float sc = __expf(m - mn);
        float ex = __expf(p - mn);
        ssum = ssum * sc + ex;
        acc[0] = acc[0] * sc + ex * x0;
        acc[1] = acc[1] * sc + ex * x1;
        acc[2] = acc[2] * sc + ex * x2;
        acc[3] = acc[3] * sc + ex * x3;
        acc[4] = acc[4] * sc + ex * x4;
        acc[5] = acc[5] * sc + ex * x5;
        acc[6] = acc[6] * sc + ex * x6;
        acc[7] = acc[7] * sc + ex * x7;
        m = mn;
    }

#pragma unroll
    for (int d = 16; d <= 32; d <<= 1) {
        float mo = __shfl_xor(m, d);
        float so = __shfl_xor(ssum, d);
        float ao[8];
#pragma unroll
        for (int j = 0; j < 8; j++) ao[j] = __shfl_xor(acc[j], d);
        float mn = fmaxf(m, mo);
        float s1 = __expf(m - mn);
        float s2 = __expf(mo - mn);
        ssum = ssum * s1 + so * s2;
#pragma unroll
        for (int j = 0; j < 8; j++) acc[j] = acc[j] * s1 + ao[j] * s2;
        m = mn;
    }

    if (grp == 0) {
        float inv = 1.f / (ssum + 1e-16f);
        const float4* cbp = (const float4*)(cb + fb);
        float4 c0 = cbp[0], c1 = cbp[1];
        float4 o0, o1;
        o0.x = fmaxf(acc[0] * inv + c0.x, 0.f);
        o0.y = fmaxf(acc[1] * inv + c0.y, 0.f);
        o0.z = fmaxf(acc[2] * inv + c0.z, 0.f);
        o0.w = fmaxf(acc[3] * inv + c0.w, 0.f);
        o1.x = fmaxf(acc[4] * inv + c1.x, 0.f);
        o1.y = fmaxf(acc[5] * inv + c1.y, 0.f);
        o1.z = fmaxf(acc[6] * inv + c1.z, 0.f);
        o1.w = fmaxf(acc[7] * inv + c1.w, 0.f);
        float4* op = (float4*)(hout + (long)node * HC + fb);
        op[0] = o0;
        op[1] = o1;
    }
}

// ---------------- h2 = relu(h @ W1 + b1) : [N,128]@[128,32] ----------------
__global__ __launch_bounds__(256) void k_mlp1(
        const float* __restrict__ h, const float* __restrict__ W1,
        const float* __restrict__ b1, float* __restrict__ h2) {
    __shared__ float hs[8 * HC];
    __shared__ float w1s[HC * DIM];
    int tid = threadIdx.x;
    long row0 = (long)blockIdx.x * 8;
    for (int idx = tid; idx < HC * DIM; idx += 256) w1s[idx] = W1[idx];
    for (int idx = tid; idx < 8 * HC; idx += 256) {
        long g = row0 * HC + idx;
        hs[idx] = (g < (long)N_NODES * HC) ? h[g] : 0.f;
    }
    __syncthreads();
    int r = tid >> 5, c = tid & 31;
    float acc = b1[c];
    for (int k = 0; k < HC; k++) acc += hs[r * HC + k] * w1s[k * DIM + c];
    long row = row0 + r;
    if (row < N_NODES) h2[row * DIM + c] = acc > 0.f ? acc : 0.f;
}

// ---------------- h3 = relu(h2 @ W2 + b2) : [N,32]@[32,16] ----------------
__global__ __launch_bounds__(256) void k_mlp2(
        const float* __restrict__ h2, const float* __restrict__ W2,
        const float* __restrict__ b2, float* __restrict__ h3) {
    __shared__ float hs[16 * DIM];
    __shared__ float w2s[DIM * DIM2];
    int tid = threadIdx.x;
    long row0 = (long)blockIdx.x * 16;
    for (int idx = tid; idx < DIM * DIM2; idx += 256) w2s[idx] = W2[idx];
    for (int idx = tid; idx < 16 * DIM; idx += 256) {
        long g = row0 * DIM + idx;
        hs[idx] = (g < (long)N_NODES * DIM) ? h2[g] : 0.f;
    }
    __syncthreads();
    int r = tid >> 4, c = tid & 15;
    float acc = b2[c];
    for (int k = 0; k < DIM; k++) acc += hs[r * DIM + k] * w2s[k * DIM2 + c];
    long row = row0 + r;
    if (row < N_NODES) h3[row * DIM2 + c] = acc > 0.f ? acc : 0.f;
}

// ------- fused head: out0 = concat(h3[src],h3[dst]) @ W3 + b3, eout = concat ----
__global__ __launch_bounds__(256) void k_out(
        const float* __restrict__ h3, const int* __restrict__ eidx,
        const float* __restrict__ W3, const float* __restrict__ b3,
        void* __restrict__ dout, const int* __restrict__ flags) {
    __shared__ float w3s[2 * DIM2 * NCLS];
    __shared__ float bs[NCLS];
    int tid = threadIdx.x;
    if (tid < 2 * DIM2 * NCLS) w3s[tid] = W3[tid];
    if (tid < NCLS) bs[tid] = b3[tid];
    __syncthreads();
    int e = blockIdx.x * 256 + tid;
    if (e >= E_EDGES) return;
    int src = eidx[e], dst = eidx[E_EDGES + e];
    float v[2 * DIM2];
    const float4* ps = (const float4*)(h3 + (long)src * DIM2);
    const float4* pd = (const float4*)(h3 + (long)dst * DIM2);
#pragma unroll
    for (int q = 0; q < 4; q++) {
        float4 t = ps[q];
        v[q * 4 + 0] = t.x; v[q * 4 + 1] = t.y; v[q * 4 + 2] = t.z; v[q * 4 + 3] = t.w;
    }
#pragma unroll
    for (int q = 0; q < 4; q++) {
        float4 t = pd[q];
        v[16 + q * 4 + 0] = t.x; v[16 + q * 4 + 1] = t.y; v[16 + q * 4 + 2] = t.z; v[16 + q * 4 + 3] = t.w;
    }
    float o[NCLS];
#pragma unroll
    for (int j = 0; j < NCLS; j++) {
        float acc = bs[j];
#pragma unroll
        for (int k = 0; k < 2 * DIM2; k++) acc += v[k] * w3s[k * NCLS + j];
        o[j] = acc;
    }
    if (flags[0]) {
        float* out0 = (float*)dout;
#pragma unroll
        for (int j = 0; j < NCLS; j++) out0[(long)e * NCLS + j] = o[j];
        float4* eo = (float4*)((float*)dout + (long)E_EDGES * NCLS) + (long)e * 8;
#pragma unroll
        for (int q = 0; q < 8; q++)
            eo[q] = make_float4(v[q * 4], v[q * 4 + 1], v[q * 4 + 2], v[q * 4 + 3]);
    } else {
        bf16* out0 = (bf16*)dout;
#pragma unroll
        for (int j = 0; j < NCLS; j++) out0[(long)e * NCLS + j] = __float2bfloat16(o[j]);
        uint4* eo = (uint4*)((bf16*)dout + (long)E_EDGES * NCLS) + (long)e * 4;
#pragma unroll
        for (int q = 0; q < 4; q++) {
            uint4 w;
            w.x = (unsigned)f2bfu(v[q * 8 + 0]) | ((unsigned)f2bfu(v[q * 8 + 1]) << 16);
            w.y = (unsigned)f2bfu(v[q * 8 + 2]) | ((unsigned)f2bfu(v[q * 8 + 3]) << 16);
            w.z = (unsigned)f2bfu(v[q * 8 + 4]) | ((unsigned)f2bfu(v[q * 8 + 5]) << 16);
            w.w = (unsigned)f2bfu(v[q * 8 + 6]) | ((unsigned)f2bfu(v[q * 8 + 7]) << 16);
            eo[q] = w;
        }
    }
}

extern "C" void kernel_launch(void* const* d_in, const int* in_sizes, int n_in,
                              void* d_out, int out_size, void* d_ws, size_t ws_size,
                              hipStream_t stream) {
    // ---- workspace layout (4-byte word offsets) ----
    float* wsf   = (float*)d_ws;
    int*   flags = (int*)d_ws;                     // 16 words
    float* h     = wsf + 16;                       // 6,400,000
    float* xl    = h  + (long)N_NODES * HC;        // 6,400,000 words reserved (xlbf uses half)
    float* xr    = xl + (long)N_NODES * HC;        // 6,400,000
    float* prm   = xr + (long)N_NODES * HC;        // 110,000
    int*   eidx  = (int*)(prm + 110000);           // 1,600,000
    int*   off   = eidx + 2 * E_EDGES;             // 50,001
    int*   fill  = off + (N_NODES + 1);            // 50,000
    int*   csr   = fill + N_NODES;                 // 850,000
    int*   part  = csr + EA;                       // 64
    unsigned short* wswz = (unsigned short*)(part + 64);  // 3*32768 ushorts
    unsigned* xlbf = (unsigned*)xl;                // N*64 packed bf16x2
    float* h2 = xl;                                // overlay (free after convs)
    float* h3 = xl + (long)N_NODES * DIM;

    // param block offsets (floats) — must match k_cvt_all's segment table
    float* pWl = prm + 0;        // 3*16384
    float* pbl = prm + 98304;
    float* pbr = prm + 98688;
    float* patt= prm + 99072;
    float* pcb = prm + 99456;
    float* pW1 = prm + 99840;
    float* pb1 = prm + 103936;
    float* pW2 = prm + 103968;
    float* pb2 = prm + 104480;
    float* pW3 = prm + 104496;
    float* pb3 = prm + 104688;

    // 1. detect dtypes (deterministic function of pristine inputs)
    k_detect<<<1, 256, 0, stream>>>(d_in[3], d_in[1], flags);

    // 2. normalize inputs; swizzle weights for MFMA
    k_cvt_all<<<(XN + 104694 + 255) / 256, 256, 0, stream>>>(
        d_in[0], d_in[3], d_in[4], d_in[5], d_in[6], d_in[7], d_in[8],
        d_in[9], d_in[10], d_in[11], d_in[12], d_in[13], d_in[14],
        h, prm, flags);
    k_cvti<<<(2 * E_EDGES + 255) / 256, 256, 0, stream>>>(d_in[1], eidx, 2 * E_EDGES, flags);
    k_wswz<<<(3 * WSWZ_L + 255) / 256, 256, 0, stream>>>(pWl, wswz);

    // 3. CSR build
    k_zero<<<(2 * N_NODES + 1 + 255) / 256, 256, 0, stream>>>(off, fill);
    k_hist<<<(EA + 255) / 256, 256, 0, stream>>>(eidx, off);
    k_scan1<<<NCHUNK, 1024, 0, stream>>>(off, part);
    k_scan2<<<1, 64, 0, stream>>>(part);
    k_scan3<<<NCHUNK, 1024, 0, stream>>>(off, part);
    k_scatter<<<(EA + 255) / 256, 256, 0, stream>>>(eidx, off, fill, csr);

    // 4. three GATv2 layers (h updated in place by k_attn)
    for (int i = 0; i < 3; i++) {
        k_gemm_mfma<<<(N_NODES + GM - 1) / GM, 256, 0, stream>>>(
            h, wswz + (long)i * WSWZ_L, pbl + (long)i * HC, pbr + (long)i * HC,
            xlbf, xr);
        k_attn<<<(N_NODES + 3) / 4, 256, 0, stream>>>(
            xlbf, xr, off, csr, patt + (long)i * HEADS * DIM, pcb + (long)i * HC, h);
    }

    // 5. MLP head
    k_mlp1<<<(N_NODES + 7) / 8, 256, 0, stream>>>(h, pW1, pb1, h2);
    k_mlp2<<<(N_NODES + 15) / 16, 256, 0, stream>>>(h2, pW2, pb2, h3);

    // 6. fused outputs (single gather of h3 rows)
    k_out<<<(E_EDGES + 255) / 256, 256, 0, stream>>>(h3, eidx, pW3, pb3, d_out, flags);
}